// Round 9
// baseline (593.984 us; speedup 1.0000x reference)
//
#include <hip/hip_runtime.h>

// Voxel pooling R9: coarse (b,y) bins with dense cursor-allocated writes
// (kills per-XCD line-eviction amplification: R4/R7/R8 all showed ~64 B
// writeback per scattered 8 B payload store), line-padded counters (kills
// per-line atomic serialization), and an LDS-tile gather (one block per
// (b,y), 128x80 fp32 accumulated with ds_add_f32, coalesced tile store).

namespace {
constexpr int NVX = 128, NVY = 128, C = 80;
constexpr int B = 2, N = 6, D = 112, H = 16, W = 44;
constexpr int HW    = H * W;             // 704
constexpr int BN    = B * N;             // 12
constexpr int DHW   = D * HW;            // 78848
constexpr int NDHW  = N * DHW;           // 473088 (points per batch)
constexpr int TOTAL = B * NDHW;          // 946176
constexpr int NROW  = BN * HW;           // 8448 ctx_t rows (14 bits)
constexpr int NBIN  = B * NVY;           // 256 bins = (b, y)
constexpr int NGRP  = 8;                 // sub-lists per bin (XCD heuristic)
constexpr int SUBCAP   = 640;            // lambda=462, +8 sigma
constexpr int CNT_STRIDE = 16;           // one counter per 64 B line
constexpr int SPILLCAP = 32768;

constexpr int HIST_BLOCKS = TOTAL / 4 / 256;            // 924 (exact)
constexpr int TR_BLOCKS   = BN * (C / 16) * (HW / 64);  // 660
constexpr int PRE_BLOCKS  = HIST_BLOCKS + TR_BLOCKS;    // 1584
constexpr int ACC_PITCH = 81;            // LDS row stride (odd mod 32 cosets)
}

typedef int   vint4   __attribute__((ext_vector_type(4)));
typedef float vfloat4 __attribute__((ext_vector_type(4)));

// ---- 1. fused: hist_fill (blocks < HIST_BLOCKS) | tiled transpose ----
__global__ __launch_bounds__(256) void pre_kernel(
    const int*   __restrict__ geom, const float* __restrict__ depth,
    const float* __restrict__ ctx,  float* __restrict__ ctx_t,
    int* __restrict__ counts, unsigned long long* __restrict__ bins,
    int* __restrict__ spillcnt, unsigned long long* __restrict__ spill)
{
    __shared__ float tile[16 * 68];
    if (blockIdx.x < HIST_BLOCKS) {
        const int grp = blockIdx.x & 7;              // XCD round-robin heuristic
        const int t   = blockIdx.x * 256 + threadIdx.x;
        const int p0  = t * 4;
        const vint4* g4 = (const vint4*)(geom + (size_t)3 * p0);
        const vint4 ga = g4[0];
        const vint4 gb = g4[1];
        const vint4 gc = g4[2];
        const vfloat4 dp = *(const vfloat4*)(depth + p0);
        const int xs[4] = {ga.x, ga.w, gb.z, gc.y};
        const int ys[4] = {ga.y, gb.x, gb.w, gc.z};
        const float ds[4] = {dp.x, dp.y, dp.z, dp.w};
        #pragma unroll
        for (int u = 0; u < 4; ++u) {
            const int p = p0 + u;
            const int x = xs[u], y = ys[u];
            if ((unsigned)x >= (unsigned)NVX || (unsigned)y >= (unsigned)NVY) continue;
            const int b    = (p >= NDHW) ? 1 : 0;        // B == 2
            const int bin  = b * NVY + y;                // 0..255
            const int bn   = (unsigned)p / (unsigned)DHW;
            const int hw   = (unsigned)p % (unsigned)HW;
            const int row  = bn * HW + hw;               // < 8448 (14 bits)
            const int pk   = (x << 14) | row;            // 21 bits
            const unsigned dep = (unsigned)__float_as_int(ds[u]);
            const int slot = bin * NGRP + grp;
            const int idx  = atomicAdd(&counts[slot * CNT_STRIDE], 1);
            if (idx < SUBCAP) {
                bins[(size_t)slot * SUBCAP + idx] =
                    ((unsigned long long)dep << 32) | (unsigned)pk;
            } else {
                int s = atomicAdd(&counts[NBIN * NGRP * CNT_STRIDE], 1); // spillcnt
                if (s < SPILLCAP) {
                    const int v = bin * NVX + x;         // 15 bits
                    spill[s] = ((unsigned long long)dep << 32)
                             | (unsigned)((v << 14) | row);
                }
            }
        }
    } else {
        // transpose ctx (bn, c, hw) -> ctx_t (bn*HW + hw, c), 16c x 64hw tiles
        const int tb  = blockIdx.x - HIST_BLOCKS;
        const int bn  = tb / 55;
        const int rem = tb % 55;
        const int c0  = (rem / 11) * 16;
        const int hw0 = (rem % 11) * 64;
        const int t = threadIdx.x;
        const int cl = t >> 6, hwl = t & 63;
        #pragma unroll
        for (int r = 0; r < 4; ++r) {
            const int c = r * 4 + cl;
            tile[c * 68 + hwl] =
                ctx[(size_t)(bn * C + c0 + c) * HW + hw0 + hwl];
        }
        __syncthreads();
        const int cr = t & 15, hwr = t >> 4;
        #pragma unroll
        for (int r = 0; r < 4; ++r) {
            const int hw = r * 16 + hwr;
            ctx_t[(size_t)(bn * HW + hw0 + hw) * C + c0 + cr] =
                tile[cr * 68 + hw];
        }
    }
}

// ---- 2. gather: one block per (b,y) bin; LDS 128x80 accumulator ----
__global__ __launch_bounds__(1024) void gather_kernel(
    const int* __restrict__ counts, const unsigned long long* __restrict__ bins,
    const float* __restrict__ ctx_t, float* __restrict__ out)
{
    __shared__ float acc[NVX * ACC_PITCH];               // 41.5 KB
    const int bin = blockIdx.x;
    const int tid = threadIdx.x;
    for (int i = tid; i < NVX * ACC_PITCH; i += 1024) acc[i] = 0.f;
    __syncthreads();

    const int wave = tid >> 6, lane = tid & 63;
    const int g    = wave >> 1;                          // sub-list 0..7
    const int par  = wave & 1;                           // chunk parity
    const int g3   = (lane >= 60) ? 3 : (lane / 20);     // load group
    const int r    = lane - g3 * 20;                     // float4 index in row

    int cnt = counts[(bin * NGRP + g) * CNT_STRIDE];
    if (cnt > SUBCAP) cnt = SUBCAP;
    const unsigned long long* sub = bins + (size_t)(bin * NGRP + g) * SUBCAP;
    const vfloat4* __restrict__ ctx4 = (const vfloat4*)ctx_t;

    for (int c0 = par * 64; c0 < cnt; c0 += 128) {
        const int ii = c0 + lane;
        const unsigned long long e = (ii < cnt) ? sub[ii] : 0ull;
        const int pk = (int)(unsigned)(e & 0xffffffffu);
        const int db = (int)(unsigned)(e >> 32);
        #pragma unroll
        for (int jj = 0; jj < 64; jj += 3) {
            int src = jj + g3; if (src > 63) src = 63;
            int   pks = __shfl(pk, src);
            float dps = __int_as_float(__shfl(db, src));
            const bool act = (g3 < 3) && (jj + g3 < 64);
            int row = pks & 16383;
            int xl  = pks >> 14;
            if (!act) { dps = 0.f; row = 0; xl = 0; }
            const vfloat4 cv = ctx4[row * 20 + r];
            float* a = acc + xl * ACC_PITCH + r * 4;
            atomicAdd(a + 0, dps * cv.x);
            atomicAdd(a + 1, dps * cv.y);
            atomicAdd(a + 2, dps * cv.z);
            atomicAdd(a + 3, dps * cv.w);
        }
    }
    __syncthreads();

    // coalesced tile store: out[bin*128*80 + v*80 + c]
    float* ob = out + (size_t)bin * (NVX * C);
    for (int i = tid; i < NVX * C; i += 1024) {
        const int v = i / C, c = i - v * C;
        ob[i] = acc[v * ACC_PITCH + c];
    }
}

// ---- 3. spill fixup (statistically zero work) ----
__global__ __launch_bounds__(256) void spill_kernel(
    const int* __restrict__ spillcnt, const unsigned long long* __restrict__ spill,
    const float* __restrict__ ctx_t, float* __restrict__ out)
{
    const int nwaves = gridDim.x * 4;
    const int wave   = blockIdx.x * 4 + (threadIdx.x >> 6);
    const int lane   = threadIdx.x & 63;
    int cnt = *spillcnt;
    if (cnt > SPILLCAP) cnt = SPILLCAP;
    for (int i = wave; i < cnt; i += nwaves) {
        const unsigned long long e = spill[i];
        const int key = (int)(unsigned)(e & 0xffffffffu);
        const float dep = __int_as_float((int)(unsigned)(e >> 32));
        const int v   = key >> 14;
        const int row = key & 16383;
        const float* c = ctx_t + (size_t)row * C;
        float* o = out + (size_t)v * C;
        unsafeAtomicAdd(o + lane, dep * c[lane]);
        if (lane < C - 64) unsafeAtomicAdd(o + 64 + lane, dep * c[64 + lane]);
    }
}

extern "C" void kernel_launch(void* const* d_in, const int* in_sizes, int n_in,
                              void* d_out, int out_size, void* d_ws, size_t ws_size,
                              hipStream_t stream) {
    const int*   geom  = (const int*)d_in[0];
    const float* depth = (const float*)d_in[1];
    const float* ctx   = (const float*)d_in[2];
    float*       out   = (float*)d_out;

    char* ws = (char*)d_ws;
    // counters: 2048 slots, one per 64 B line, + spillcnt line
    int* counts = (int*)ws;
    ws += ((size_t)(NBIN * NGRP + 1) * CNT_STRIDE * 4 + 255) / 256 * 256;
    int* spillcnt = counts + NBIN * NGRP * CNT_STRIDE;
    unsigned long long* bins = (unsigned long long*)ws;
    ws += ((size_t)NBIN * NGRP * SUBCAP * 8 + 255) / 256 * 256;   // 10.5 MB
    unsigned long long* spill = (unsigned long long*)ws;
    ws += ((size_t)SPILLCAP * 8 + 255) / 256 * 256;
    float* ctx_t = (float*)ws;                                     // 2.7 MB

    (void)hipMemsetAsync(counts, 0,
                         (size_t)(NBIN * NGRP + 1) * CNT_STRIDE * 4, stream);

    pre_kernel   <<<dim3(PRE_BLOCKS), dim3(256), 0, stream>>>(
                    geom, depth, ctx, ctx_t, counts, bins, spillcnt, spill);
    gather_kernel<<<dim3(NBIN), dim3(1024), 0, stream>>>(counts, bins, ctx_t, out);
    spill_kernel <<<dim3(64), dim3(256), 0, stream>>>(spillcnt, spill, ctx_t, out);
}